// Round 3
// baseline (13.762 us; speedup 1.0000x reference)
//
#include <hip/hip_runtime.h>
#include <math.h>

// Closed form (derived R2, verified vs full statevector sim in R1):
//   e0 = e2 = e3 = 0;  e1 = -cos^2(1) * cos(pi/2 * w1),  w1 = in[:,4].
// This round: pure memory-streaming optimization. One thread = 4 rows:
//   loads  = 5x float4 (80 B contiguous, dwordx4)
//   stores = 4x float4 (64 B contiguous, dwordx4)
__global__ __launch_bounds__(256) void qlayer_kernel(
    const float4* __restrict__ in4, float4* __restrict__ out4, int nquad)
{
    int t = blockIdx.x * blockDim.x + threadIdx.x;
    if (t >= nquad) return;

    // Thread t covers float indices [20t, 20t+20) = rows 4t..4t+3.
    const float4 v0 = in4[5 * t + 0];  (void)v0;  // rows' x/y/z cols (unused)
    const float4 v1 = in4[5 * t + 1];  // .x = w1(row0) at float idx 20t+4
    const float4 v2 = in4[5 * t + 2];  // .y = w1(row1) at 20t+9
    const float4 v3 = in4[5 * t + 3];  // .z = w1(row2) at 20t+14
    const float4 v4 = in4[5 * t + 4];  // .w = w1(row3) at 20t+19

    const float k = 1.5707963267948966f;   // pi/2
    const float A = -0.2919265817264289f;  // -cos^2(1)

    float e1a = A * __cosf(k * v1.x);
    float e1b = A * __cosf(k * v2.y);
    float e1c = A * __cosf(k * v3.z);
    float e1d = A * __cosf(k * v4.w);

    float4* o = out4 + 4 * t;
    o[0] = make_float4(0.0f, e1a, 0.0f, 0.0f);
    o[1] = make_float4(0.0f, e1b, 0.0f, 0.0f);
    o[2] = make_float4(0.0f, e1c, 0.0f, 0.0f);
    o[3] = make_float4(0.0f, e1d, 0.0f, 0.0f);
}

extern "C" void kernel_launch(void* const* d_in, const int* in_sizes, int n_in,
                              void* d_out, int out_size, void* d_ws, size_t ws_size,
                              hipStream_t stream) {
    const float4* in4 = (const float4*)d_in[0];
    float4* out4 = (float4*)d_out;
    const int B = in_sizes[0] / 5;   // (B,5) float32; B = 1048576 (divisible by 4)
    const int nquad = B / 4;         // threads, 4 rows each
    const int block = 256;
    const int grid = (nquad + block - 1) / block;
    qlayer_kernel<<<grid, block, 0, stream>>>(in4, out4, nquad);
}

// Round 4
// 12.185 us; speedup vs baseline: 1.1294x; 1.1294x over previous
//
#include <hip/hip_runtime.h>
#include <math.h>

// Closed form (derived R2, verified vs full statevector sim in R1):
//   e0 = e2 = e3 = 0;  e1 = -cos^2(1) * cos(pi/2 * w1),  w1 = in[:,4].
//
// R4: both global streams per-instruction coalesced via LDS staging.
//   load : 5x float4/thread, lane-contiguous (1 KB per wave instruction)
//   store: 4x float4/thread, lane-contiguous (1 KB per wave instruction)
//   LDS  : 20 KB/block; stride-5 float reads -> 2 lanes/bank (free on CDNA4)

#define ROWS_PER_BLOCK 1024  // 5120 floats = 1280 float4 staged per block

__global__ __launch_bounds__(256) void qlayer_kernel(
    const float4* __restrict__ in4, float4* __restrict__ out4)
{
    __shared__ float lds[5 * ROWS_PER_BLOCK];
    const int tid = threadIdx.x;
    const int in4Base = blockIdx.x * (5 * ROWS_PER_BLOCK / 4);
    const int outBase = blockIdx.x * ROWS_PER_BLOCK;

    float4* lds4 = reinterpret_cast<float4*>(lds);
#pragma unroll
    for (int j = 0; j < 5; ++j)
        lds4[j * 256 + tid] = in4[in4Base + j * 256 + tid];
    __syncthreads();

    const float k = 1.5707963267948966f;   // pi/2
    const float A = -0.2919265817264289f;  // -cos^2(1)
#pragma unroll
    for (int c = 0; c < 4; ++c) {
        const int r = c * 256 + tid;            // row within block chunk
        const float w = lds[5 * r + 4];         // w1 of that row
        out4[outBase + r] = make_float4(0.0f, A * __cosf(k * w), 0.0f, 0.0f);
    }
}

// Scalar tail (only launched if B % ROWS_PER_BLOCK != 0; B=1M -> unused).
__global__ __launch_bounds__(256) void qlayer_tail(
    const float* __restrict__ in, float4* __restrict__ out4, int start, int B)
{
    int b = start + blockIdx.x * blockDim.x + threadIdx.x;
    if (b >= B) return;
    const float w = in[5 * b + 4];
    out4[b] = make_float4(0.0f, -0.2919265817264289f * __cosf(1.5707963267948966f * w),
                          0.0f, 0.0f);
}

extern "C" void kernel_launch(void* const* d_in, const int* in_sizes, int n_in,
                              void* d_out, int out_size, void* d_ws, size_t ws_size,
                              hipStream_t stream) {
    const float* in = (const float*)d_in[0];
    const float4* in4 = (const float4*)d_in[0];
    float4* out4 = (float4*)d_out;
    const int B = in_sizes[0] / 5;          // (B,5) float32
    const int nb = B / ROWS_PER_BLOCK;      // full blocks
    if (nb > 0)
        qlayer_kernel<<<nb, 256, 0, stream>>>(in4, out4);
    const int done = nb * ROWS_PER_BLOCK;
    if (done < B) {
        const int rem = B - done;
        qlayer_tail<<<(rem + 255) / 256, 256, 0, stream>>>(in, out4, done, B);
    }
}